// Round 1
// 512.846 us; speedup vs baseline: 1.0236x; 1.0236x over previous
//
#include <hip/hip_runtime.h>
#include <math.h>

typedef _Float16 f16_t;
typedef _Float16 f16x8 __attribute__((ext_vector_type(8)));
typedef _Float16 f16x4 __attribute__((ext_vector_type(4)));
typedef float    f32x4 __attribute__((ext_vector_type(4)));

#define NHC 128          // NH
#define NBATCH 16
#define JT 64            // output cols per block
#define THREADS 512
#define LDSROWPITCH 272  // 128*2 bytes + 16 pad -> 2-way-max bank aliasing on b128 reads
#define LDSREGION (66*LDSROWPITCH)

__device__ __host__ __forceinline__ int nstep_f(int n){ int m = n - 4; m = m < 0 ? 0 : m; return ((m + 1) >> 1) + 1; }

// ---------------- prep: W[c][i][k] fp32 -> Wt[k][c][i] fp16; depth-channel prefix sums; fp32 bias ----------------
__global__ void prep_kernel(const float* __restrict__ W, const float* __restrict__ bin,
                            f16_t* __restrict__ Wt, float* __restrict__ Pp, float* __restrict__ biasf)
{
    int c = blockIdx.x;      // 0..383
    int i = threadIdx.x;     // 0..127
    #pragma unroll
    for (int k = 0; k < 4; k++)
        Wt[((size_t)k*384 + c)*128 + i] = (f16_t)W[((size_t)c*129 + i)*4 + k];
    if (i == 0) {
        float s = 0.f;
        Pp[c*5 + 0] = 0.f;
        #pragma unroll
        for (int k = 0; k < 4; k++) { s += W[((size_t)c*129 + 128)*4 + k]; Pp[c*5 + k + 1] = s; }
        biasf[c] = bin[c];
    }
}

// ---------------- transpose h (B,NH,L0) fp32 -> X0 (B, pos, 128 ch) fp16, mask p>=N ----------------
__global__ void transpose_kernel(const float* __restrict__ h, const int* __restrict__ N0,
                                 f16_t* __restrict__ X0, int outCols)
{
    __shared__ float tile[32][65];
    const int b = blockIdx.z, c0 = blockIdx.y*32, p0 = blockIdx.x*64;
    const int tid = threadIdx.x;
    const int n0 = N0[b];
    const int L0c = 16384;
    {
        int c = tid >> 3, pc = (tid & 7) * 8;
        const float* src = h + ((size_t)b*NHC + c0 + c)*L0c + p0 + pc;
        float4 v0 = *(const float4*)(src);
        float4 v1 = *(const float4*)(src + 4);
        *(float4*)(&tile[c][pc])     = v0;
        *(float4*)(&tile[c][pc + 4]) = v1;
    }
    __syncthreads();
    {
        int p = tid >> 2, cc = (tid & 3) * 8;
        bool dead = (p0 + p >= n0);
        f16x8 vv;
        #pragma unroll
        for (int e = 0; e < 8; e++) vv[e] = dead ? (f16_t)0.f : (f16_t)tile[cc + e][p];
        *(f16x8*)(X0 + ((size_t)b*outCols + p0 + p)*NHC + c0 + cc) = vv;
    }
}

// ---------------- shared GEMM (384 x JT, K=4 taps x 128) + gated epilogue (conv path) ----------------
template<bool TO_LDS>
__device__ __forceinline__ void gemm_epilogue(
    const char* ldsIn, char* ldsOut, f16_t* goutB,
    const f16_t* __restrict__ Wt, const float* __restrict__ Pp,
    const float* __restrict__ biasf, float* __restrict__ outrow,
    int j0, int Nt, int Nt1, float dval, bool record)
{
    const int tid  = threadIdx.x;
    const int w    = tid >> 6;
    const int lane = tid & 63;
    const int n16  = lane & 15;
    const int q    = lane >> 4;

    f32x4 acc[3][4] = {};   // [segment l/r/g][col-tile]

    const int arow = w*16 + n16;   // A row (out-channel) within a 128-row segment
    #pragma unroll 1
    for (int k = 0; k < 4; k++) {
        const char*  bb0 = ldsIn + (k&1)*LDSREGION + ((k>>1) + n16)*LDSROWPITCH + q*16;
        const f16_t* ab  = Wt + ((size_t)k*384 + arow)*128 + q*8;
        #pragma unroll 1
        for (int kc = 0; kc < 4; kc++) {
            f16x8 a0 = *(const f16x8*)(ab + kc*32);
            f16x8 a1 = *(const f16x8*)(ab + 16384 + kc*32);   // +128 rows
            f16x8 a2 = *(const f16x8*)(ab + 32768 + kc*32);   // +256 rows
            #pragma unroll
            for (int ct = 0; ct < 4; ct++) {
                f16x8 bb = *(const f16x8*)(bb0 + ct*(16*LDSROWPITCH) + kc*64);
                acc[0][ct] = __builtin_amdgcn_mfma_f32_16x16x32_f16(a0, bb, acc[0][ct], 0, 0, 0);
                acc[1][ct] = __builtin_amdgcn_mfma_f32_16x16x32_f16(a1, bb, acc[1][ct], 0, 0, 0);
                acc[2][ct] = __builtin_amdgcn_mfma_f32_16x16x32_f16(a2, bb, acc[2][ct], 0, 0, 0);
            }
        }
    }

    if constexpr (TO_LDS) __syncthreads();   // all reads done before in-place LDS writes

    const int cw = w*16 + q*4;   // output channel base for this lane's C-fragment rows
    float biasr[3][4], pfull[3][4];
    #pragma unroll
    for (int s = 0; s < 3; s++)
        #pragma unroll
        for (int r = 0; r < 4; r++) {
            int row = s*128 + cw + r;
            biasr[s][r] = biasf[row];
            pfull[s][r] = Pp[row*5 + 4];
        }

    #pragma unroll
    for (int ct = 0; ct < 4; ct++) {
        int j = j0 + ct*16 + n16;
        int cnt = Nt - 2*j; cnt = cnt < 0 ? 0 : (cnt > 4 ? 4 : cnt);
        bool zero = (j >= Nt1);
        float hv[4];
        #pragma unroll
        for (int r = 0; r < 4; r++) {
            float d0, d1, d2;
            if (cnt == 4)      { d0 = pfull[0][r]; d1 = pfull[1][r]; d2 = pfull[2][r]; }
            else if (cnt == 0) { d0 = 0.f; d1 = 0.f; d2 = 0.f; }
            else { int rw = cw + r; d0 = Pp[rw*5 + cnt]; d1 = Pp[(128+rw)*5 + cnt]; d2 = Pp[(256+rw)*5 + cnt]; }
            float lv = acc[0][ct][r] + biasr[0][r] + dval*d0;
            float rp = acc[1][ct][r] + biasr[1][r] + dval*d1;
            float gp = acc[2][ct][r] + biasr[2][r] + dval*d2;
            float e2 = __expf(2.f*rp);
            float rv = 1.f - 2.f/(e2 + 1.f);          // tanh
            float gv = 1.f/(1.f + __expf(-gp));       // sigmoid
            float hh = lv*gv + rv*(1.f - gv);
            hv[r] = zero ? 0.f : hh;
        }
        f16x4 hb;
        #pragma unroll
        for (int r = 0; r < 4; r++) hb[r] = (f16_t)hv[r];
        if constexpr (TO_LDS) {
            *(f16x4*)(ldsOut + (j&1)*LDSREGION + (j>>1)*LDSROWPITCH + cw*2) = hb;
        } else {
            *(f16x4*)(goutB + (ct*16 + n16)*NHC + cw) = hb;
        }
        if (record && ct == 0 && n16 == 0) {
            #pragma unroll
            for (int r = 0; r < 4; r++) outrow[cw + r] = hv[r];
        }
    }
}

// ---------------- one conv depth: X_t -> X_{t+1} ----------------
__global__ __launch_bounds__(THREADS) void conv_kernel(
    const f16_t* __restrict__ Xin, f16_t* __restrict__ Xout,
    const f16_t* __restrict__ Wt, const float* __restrict__ Pp,
    const float* __restrict__ biasf, const int* __restrict__ N0,
    float* __restrict__ outbuf,
    int t, int inCols, int outCols, float dval)
{
    __shared__ alignas(16) char ldsX[2*LDSREGION];
    const int b  = blockIdx.y;
    const int j0 = blockIdx.x * JT;
    const int tid = threadIdx.x;
    int Nt = N0[b];
    for (int s = 0; s < t; s++) Nt = nstep_f(Nt);
    const int Nt1 = nstep_f(Nt);

    f16_t* XoutB = Xout + ((size_t)b*outCols + j0)*NHC;
    if (j0 >= Nt1) {                         // fully-masked tile: just zero it
        float4 z = {0.f,0.f,0.f,0.f};
        float4* p = (float4*)XoutB;
        #pragma unroll
        for (int i = 0; i < 2; i++) p[i*THREADS + tid] = z;
        return;
    }

    // stage up to 130 input rows (pos-major, 256B each) into parity-split padded LDS
    const char* XinB = (const char*)(Xin + ((size_t)b*inCols + 2*(size_t)j0)*NHC);
    const int maxrow = inCols - 2*j0;        // rows available in this batch's buffer
    for (int it = 0; it < 5; ++it) {
        int idx = it*THREADS + tid;
        if (idx < 130*16) {
            int row = idx >> 4, cb = (idx & 15) * 16;
            float4 v = {0.f,0.f,0.f,0.f};
            if (row < maxrow) v = *(const float4*)(XinB + row*256 + cb);
            *(float4*)(ldsX + (row&1)*LDSREGION + (row>>1)*LDSROWPITCH + cb) = v;
        }
    }
    __syncthreads();

    bool newly = (Nt1 == 1) && (t == 0 || Nt > 1);
    gemm_epilogue<false>(ldsX, nullptr, XoutB, Wt, Pp, biasf, outbuf + b*NHC,
                         j0, Nt, Nt1, dval, newly && (j0 == 0));
}

// ---------------- tail: one fully-unrolled depth iteration, CTM live column-tiles ----------------
// In-place LDS safety: writes cover cols [0, 16*CTM) with zeros past Nt1; next depth reads rows
// only up to 2*nstep(Nt1)+1 <= 16*CTM-1 (verified for all Nt1), so skipped tiles are never read.
template<int CTM>
__device__ __forceinline__ void tail_iter(
    char* ldsX, const f16_t* __restrict__ Wt, const float* __restrict__ Pp,
    float* __restrict__ outrow,
    const float (&biasr)[3][4], const float (&pfull)[3][4],
    int n16, int q, int arow, int cw,
    int Nt, int Nt1, float dval, bool newly)
{
    f32x4 acc[3][CTM] = {};
    #pragma unroll
    for (int k = 0; k < 4; k++) {
        const char*  bb0 = ldsX + (k&1)*LDSREGION + ((k>>1) + n16)*LDSROWPITCH + q*16;
        const f16_t* ab  = Wt + ((size_t)k*384 + arow)*128 + q*8;
        #pragma unroll
        for (int kc = 0; kc < 4; kc++) {
            f16x8 a0 = *(const f16x8*)(ab + kc*32);
            f16x8 a1 = *(const f16x8*)(ab + 16384 + kc*32);   // +128 rows
            f16x8 a2 = *(const f16x8*)(ab + 32768 + kc*32);   // +256 rows
            #pragma unroll
            for (int ct = 0; ct < CTM; ct++) {
                f16x8 bb = *(const f16x8*)(bb0 + ct*(16*LDSROWPITCH) + kc*64);
                acc[0][ct] = __builtin_amdgcn_mfma_f32_16x16x32_f16(a0, bb, acc[0][ct], 0, 0, 0);
                acc[1][ct] = __builtin_amdgcn_mfma_f32_16x16x32_f16(a1, bb, acc[1][ct], 0, 0, 0);
                acc[2][ct] = __builtin_amdgcn_mfma_f32_16x16x32_f16(a2, bb, acc[2][ct], 0, 0, 0);
            }
        }
    }

    __syncthreads();   // all LDS reads complete before in-place writes

    #pragma unroll
    for (int ct = 0; ct < CTM; ct++) {
        int j = ct*16 + n16;
        int cnt = Nt - 2*j; cnt = cnt < 0 ? 0 : (cnt > 4 ? 4 : cnt);
        bool zero = (j >= Nt1);
        float hv[4];
        #pragma unroll
        for (int r = 0; r < 4; r++) {
            float d0, d1, d2;
            if (cnt == 4)      { d0 = pfull[0][r]; d1 = pfull[1][r]; d2 = pfull[2][r]; }
            else if (cnt == 0) { d0 = 0.f; d1 = 0.f; d2 = 0.f; }
            else { int rw = cw + r; d0 = Pp[rw*5 + cnt]; d1 = Pp[(128+rw)*5 + cnt]; d2 = Pp[(256+rw)*5 + cnt]; }
            float lv = acc[0][ct][r] + biasr[0][r] + dval*d0;
            float rp = acc[1][ct][r] + biasr[1][r] + dval*d1;
            float gp = acc[2][ct][r] + biasr[2][r] + dval*d2;
            float e2 = __expf(2.f*rp);
            float rv = 1.f - 2.f/(e2 + 1.f);          // tanh
            float gv = 1.f/(1.f + __expf(-gp));       // sigmoid
            float hh = lv*gv + rv*(1.f - gv);
            hv[r] = zero ? 0.f : hh;
        }
        f16x4 hb;
        #pragma unroll
        for (int r = 0; r < 4; r++) hb[r] = (f16_t)hv[r];
        *(f16x4*)(ldsX + (j&1)*LDSREGION + (j>>1)*LDSROWPITCH + cw*2) = hb;
        if (newly && ct == 0 && n16 == 0) {
            #pragma unroll
            for (int r = 0; r < 4; r++) outrow[cw + r] = hv[r];
        }
    }
}

// ---------------- tail: depths 7..12 entirely in LDS, one block per batch ----------------
__global__ __launch_bounds__(THREADS) void tail_kernel(
    const f16_t* __restrict__ Xin, const f16_t* __restrict__ Wt,
    const float* __restrict__ Pp, const float* __restrict__ biasf,
    const int* __restrict__ N0, float* __restrict__ outbuf, int inCols)
{
    __shared__ alignas(16) char ldsX[2*LDSREGION];
    const int b = blockIdx.x;
    const int tid = threadIdx.x;
    int Nt = N0[b];
    for (int s = 0; s < 7; s++) Nt = nstep_f(Nt);
    if (Nt <= 1) return;                     // finished during conv phase; already recorded

    const char* XinB = (const char*)(Xin + (size_t)b*inCols*NHC);
    for (int it = 0; it < 5; ++it) {
        int idx = it*THREADS + tid;
        if (idx < 130*16) {
            int row = idx >> 4, cb = (idx & 15) * 16;
            float4 v = {0.f,0.f,0.f,0.f};
            if (row < inCols) v = *(const float4*)(XinB + row*256 + cb);
            *(float4*)(ldsX + (row&1)*LDSREGION + (row>>1)*LDSROWPITCH + cb) = v;
        }
    }

    const int w    = tid >> 6;
    const int lane = tid & 63;
    const int n16  = lane & 15;
    const int q    = lane >> 4;
    const int arow = w*16 + n16;
    const int cw   = w*16 + q*4;
    float* outrow  = outbuf + b*NHC;

    // depth-invariant epilogue parameters, hoisted out of the depth loop
    float biasr[3][4], pfull[3][4];
    #pragma unroll
    for (int s = 0; s < 3; s++)
        #pragma unroll
        for (int r = 0; r < 4; r++) {
            int row = s*128 + cw + r;
            biasr[s][r] = biasf[row];
            pfull[s][r] = Pp[row*5 + 4];
        }
    __syncthreads();

    for (int t = 7; t < 13; ++t) {
        int Nt1 = nstep_f(Nt);
        bool newly = (Nt1 == 1);             // Nt > 1 guaranteed inside the loop
        float dval = log1pf((float)t);
        int ctmax = (Nt1 >> 4) + 1; if (ctmax > 4) ctmax = 4;
        switch (ctmax) {
        case 1:  tail_iter<1>(ldsX, Wt, Pp, outrow, biasr, pfull, n16, q, arow, cw, Nt, Nt1, dval, newly); break;
        case 2:  tail_iter<2>(ldsX, Wt, Pp, outrow, biasr, pfull, n16, q, arow, cw, Nt, Nt1, dval, newly); break;
        case 3:  tail_iter<3>(ldsX, Wt, Pp, outrow, biasr, pfull, n16, q, arow, cw, Nt, Nt1, dval, newly); break;
        default: tail_iter<4>(ldsX, Wt, Pp, outrow, biasr, pfull, n16, q, arow, cw, Nt, Nt1, dval, newly); break;
        }
        if (newly) return;                   // result recorded; this batch is done
        Nt = Nt1;
        __syncthreads();                     // writes visible before next depth's reads
    }
}

// ---------------- finalize: stable rank by finish depth, emit fp32 ----------------
__global__ void finalize_kernel(const float* __restrict__ outbuf,
                                const int* __restrict__ N0, float* __restrict__ dout)
{
    __shared__ int fin[16];
    __shared__ int rnk[16];
    int tid = threadIdx.x;
    if (tid < 16) {
        int n = N0[tid]; int f = 12;
        for (int t = 0; t < 13; t++) { n = nstep_f(n); if (n == 1) { f = t; break; } }
        fin[tid] = f;
    }
    __syncthreads();
    if (tid < 16) {
        int r = 0;
        for (int b2 = 0; b2 < 16; b2++)
            if (fin[b2] < fin[tid] || (fin[b2] == fin[tid] && b2 < tid)) r++;
        rnk[tid] = r;
    }
    __syncthreads();
    for (int e = tid; e < NBATCH*NHC; e += 256) {
        int b = e >> 7, c = e & 127;
        dout[rnk[b]*NHC + c] = outbuf[e];
    }
}

extern "C" void kernel_launch(void* const* d_in, const int* in_sizes, int n_in,
                              void* d_out, int out_size, void* d_ws, size_t ws_size,
                              hipStream_t stream)
{
    const float* h    = (const float*)d_in[0];
    const int*   N0   = (const int*)d_in[1];
    const float* W    = (const float*)d_in[2];
    const float* bvec = (const float*)d_in[3];
    float* dout = (float*)d_out;

    int Ls[14], Ms[14];
    Ls[0] = 16384;
    for (int t = 0; t < 13; t++) Ls[t+1] = nstep_f(Ls[t]);
    for (int t = 0; t < 14; t++) Ms[t] = ((Ls[t] + 63) / 64) * 64;

    char* ws = (char*)d_ws;
    size_t off = 0;
    auto alloc = [&](size_t bytes){ size_t o = off; off += (bytes + 255) & ~(size_t)255; return o; };
    size_t oXA   = alloc((size_t)NBATCH * Ms[0] * NHC * 2);
    size_t oXB   = alloc((size_t)NBATCH * Ms[1] * NHC * 2);
    size_t oWt   = alloc((size_t)4*384*128*2);
    size_t oPp   = alloc((size_t)384*5*4);
    size_t oBias = alloc((size_t)384*4);
    size_t oOut  = alloc((size_t)NBATCH*NHC*4);
    f16_t* XA    = (f16_t*)(ws + oXA);
    f16_t* XB    = (f16_t*)(ws + oXB);
    f16_t* Wt    = (f16_t*)(ws + oWt);
    float* Pp    = (float*)(ws + oPp);
    float* biasf = (float*)(ws + oBias);
    float* outb  = (float*)(ws + oOut);

    hipLaunchKernelGGL(prep_kernel, dim3(384), dim3(128), 0, stream, W, bvec, Wt, Pp, biasf);
    hipLaunchKernelGGL(transpose_kernel, dim3(Ms[0]/64, 4, NBATCH), dim3(256), 0, stream, h, N0, XA, Ms[0]);

    f16_t* cur = XA; f16_t* nxt = XB;
    for (int t = 0; t < 7; t++) {
        hipLaunchKernelGGL(conv_kernel, dim3(Ms[t+1]/64, NBATCH), dim3(THREADS), 0, stream,
                           cur, nxt, Wt, Pp, biasf, N0, outb, t, Ms[t], Ms[t+1], log1pf((float)t));
        f16_t* tmp = cur; cur = nxt; nxt = tmp;
    }
    // cur == X7
    hipLaunchKernelGGL(tail_kernel, dim3(NBATCH), dim3(THREADS), 0, stream,
                       cur, Wt, Pp, biasf, N0, outb, Ms[7]);
    hipLaunchKernelGGL(finalize_kernel, dim3(1), dim3(256), 0, stream, outb, N0, dout);
}